// Round 1
// baseline (6312.100 us; speedup 1.0000x reference)
//
#include <hip/hip_runtime.h>
#include <math.h>

#define KN 100   // neighbors per node
#define DD 64    // embedding dim
#define XS 129   // X row stride (129 % 32 == 1 -> conflict-free for lane=row access)

// Pool a group of KK output rows (k0..k0+KK-1) for one source (user or item).
// scr rows are wave-uniform -> scalar loads; E comes from LDS.
template <int KK>
__device__ __forceinline__ void pool_rows(const float* __restrict__ scr,
                                          const int* __restrict__ nbs, int k0,
                                          int tx, int xoff,
                                          const float (*__restrict__ sE)[DD],
                                          float (*__restrict__ sX)[XS]) {
  const float4* sp[KK];
#pragma unroll
  for (int c = 0; c < KK; ++c) {
    int row = __builtin_amdgcn_readfirstlane(nbs[k0 + c]);
    sp[c] = reinterpret_cast<const float4*>(scr + (size_t)row * KN);
  }
  float acc[KK];
#pragma unroll
  for (int c = 0; c < KK; ++c) acc[c] = 0.f;
  for (int jj = 0; jj < KN / 4; ++jj) {
    const float e0 = sE[jj * 4 + 0][tx];
    const float e1 = sE[jj * 4 + 1][tx];
    const float e2 = sE[jj * 4 + 2][tx];
    const float e3 = sE[jj * 4 + 3][tx];
#pragma unroll
    for (int c = 0; c < KK; ++c) {
      float4 v = sp[c][jj];
      acc[c] = fmaf(v.x, e0, acc[c]);
      acc[c] = fmaf(v.y, e1, acc[c]);
      acc[c] = fmaf(v.z, e2, acc[c]);
      acc[c] = fmaf(v.w, e3, acc[c]);
    }
  }
#pragma unroll
  for (int c = 0; c < KK; ++c) sX[k0 + c][xoff + tx] = acc[c];
}

__launch_bounds__(256, 1)
__global__ void cnn_fused(
    const float* __restrict__ user_emb, const float* __restrict__ item_emb,
    const float* __restrict__ user_scr, const float* __restrict__ item_scr,
    const float* __restrict__ w1, const float* __restrict__ b1,
    const float* __restrict__ w2, const float* __restrict__ b2,
    const float* __restrict__ w3, const float* __restrict__ b3,
    const float* __restrict__ w4, const float* __restrict__ b4,
    const float* __restrict__ w5, const float* __restrict__ b5,
    const int* __restrict__ user_idx_t, const int* __restrict__ item_idx_t,
    const int* __restrict__ user_idxs, const int* __restrict__ item_idxs,
    float* __restrict__ out) {
  __shared__ int s_nb[2][KN];
  __shared__ float s_E[2][KN][DD];      // gathered embeddings (user, item)
  __shared__ float s_X[KN + 1][XS];     // row KN = dummy row for inactive lanes
  __shared__ float s_part[4];

  const int b = blockIdx.x;
  const int tid = threadIdx.x;
  const int tx = tid & 63;
  const int ty = tid >> 6;

  // ---- phase 0: neighbor index lists ----
  if (tid < KN) {
    s_nb[0][tid] = user_idx_t[(size_t)user_idxs[b] * KN + tid];
  } else if (tid >= 128 && tid < 128 + KN) {
    s_nb[1][tid - 128] = item_idx_t[(size_t)item_idxs[b] * KN + (tid - 128)];
  }
  __syncthreads();

  // ---- phase 1: gather embeddings into LDS (coalesced 256B rows) ----
  for (int r = ty; r < KN; r += 4) {
    s_E[0][r][tx] = user_emb[(size_t)s_nb[0][r] * DD + tx];
    s_E[1][r][tx] = item_emb[(size_t)s_nb[1][r] * DD + tx];
  }
  __syncthreads();

  // ---- phase 2: scored pooling. wave ty owns rows [ty*25, ty*25+25) ----
  {
    const int base = ty * 25;
    pool_rows<10>(user_scr, s_nb[0], base + 0, tx, 0, s_E[0], s_X);
    pool_rows<10>(user_scr, s_nb[0], base + 10, tx, 0, s_E[0], s_X);
    pool_rows<5>(user_scr, s_nb[0], base + 20, tx, 0, s_E[0], s_X);
    pool_rows<10>(item_scr, s_nb[1], base + 0, tx, DD, s_E[1], s_X);
    pool_rows<10>(item_scr, s_nb[1], base + 10, tx, DD, s_E[1], s_X);
    pool_rows<5>(item_scr, s_nb[1], base + 20, tx, DD, s_E[1], s_X);
  }
  __syncthreads();

  // ---- phase 3: MLP, one k-row per lane (25 active lanes per wave) ----
  const bool act = tx < 25;
  const int kc = act ? (ty * 25 + tx) : KN;  // inactive lanes -> dummy row

  float xv[128];
#pragma unroll
  for (int i = 0; i < 128; ++i) xv[i] = s_X[kc][i];

  // L1: 128 -> 64 (relu), out to s_X[kc][0..63]
#pragma unroll 1
  for (int o = 0; o < 64; o += 4) {
    const float* r0 = w1 + (size_t)o * 128;
    const float* r1 = r0 + 128;
    const float* r2 = r1 + 128;
    const float* r3 = r2 + 128;
    float a0 = b1[o], a1 = b1[o + 1], a2 = b1[o + 2], a3 = b1[o + 3];
#pragma unroll
    for (int i = 0; i < 128; ++i) {
      const float x = xv[i];
      a0 = fmaf(r0[i], x, a0);
      a1 = fmaf(r1[i], x, a1);
      a2 = fmaf(r2[i], x, a2);
      a3 = fmaf(r3[i], x, a3);
    }
    s_X[kc][o + 0] = fmaxf(a0, 0.f);
    s_X[kc][o + 1] = fmaxf(a1, 0.f);
    s_X[kc][o + 2] = fmaxf(a2, 0.f);
    s_X[kc][o + 3] = fmaxf(a3, 0.f);
  }
  float hv[64];
#pragma unroll
  for (int i = 0; i < 64; ++i) hv[i] = s_X[kc][i];

  // L2: 64 -> 64 (relu), out to s_X[kc][64..127]
#pragma unroll 1
  for (int o = 0; o < 64; o += 4) {
    const float* r0 = w2 + (size_t)o * 64;
    const float* r1 = r0 + 64;
    const float* r2 = r1 + 64;
    const float* r3 = r2 + 64;
    float a0 = b2[o], a1 = b2[o + 1], a2 = b2[o + 2], a3 = b2[o + 3];
#pragma unroll
    for (int i = 0; i < 64; ++i) {
      const float x = hv[i];
      a0 = fmaf(r0[i], x, a0);
      a1 = fmaf(r1[i], x, a1);
      a2 = fmaf(r2[i], x, a2);
      a3 = fmaf(r3[i], x, a3);
    }
    s_X[kc][64 + o + 0] = fmaxf(a0, 0.f);
    s_X[kc][64 + o + 1] = fmaxf(a1, 0.f);
    s_X[kc][64 + o + 2] = fmaxf(a2, 0.f);
    s_X[kc][64 + o + 3] = fmaxf(a3, 0.f);
  }
  float gv[64];
#pragma unroll
  for (int i = 0; i < 64; ++i) gv[i] = s_X[kc][64 + i];

  // L3: 64 -> 32 (relu), out to s_X[kc][0..31]
#pragma unroll 1
  for (int o = 0; o < 32; o += 4) {
    const float* r0 = w3 + (size_t)o * 64;
    const float* r1 = r0 + 64;
    const float* r2 = r1 + 64;
    const float* r3 = r2 + 64;
    float a0 = b3[o], a1 = b3[o + 1], a2 = b3[o + 2], a3 = b3[o + 3];
#pragma unroll
    for (int i = 0; i < 64; ++i) {
      const float x = gv[i];
      a0 = fmaf(r0[i], x, a0);
      a1 = fmaf(r1[i], x, a1);
      a2 = fmaf(r2[i], x, a2);
      a3 = fmaf(r3[i], x, a3);
    }
    s_X[kc][o + 0] = fmaxf(a0, 0.f);
    s_X[kc][o + 1] = fmaxf(a1, 0.f);
    s_X[kc][o + 2] = fmaxf(a2, 0.f);
    s_X[kc][o + 3] = fmaxf(a3, 0.f);
  }
  float pv[32];
#pragma unroll
  for (int i = 0; i < 32; ++i) pv[i] = s_X[kc][i];

  // L4: 32 -> 32 (relu), out to s_X[kc][32..63]
#pragma unroll 1
  for (int o = 0; o < 32; o += 4) {
    const float* r0 = w4 + (size_t)o * 32;
    const float* r1 = r0 + 32;
    const float* r2 = r1 + 32;
    const float* r3 = r2 + 32;
    float a0 = b4[o], a1 = b4[o + 1], a2 = b4[o + 2], a3 = b4[o + 3];
#pragma unroll
    for (int i = 0; i < 32; ++i) {
      const float x = pv[i];
      a0 = fmaf(r0[i], x, a0);
      a1 = fmaf(r1[i], x, a1);
      a2 = fmaf(r2[i], x, a2);
      a3 = fmaf(r3[i], x, a3);
    }
    s_X[kc][32 + o + 0] = fmaxf(a0, 0.f);
    s_X[kc][32 + o + 1] = fmaxf(a1, 0.f);
    s_X[kc][32 + o + 2] = fmaxf(a2, 0.f);
    s_X[kc][32 + o + 3] = fmaxf(a3, 0.f);
  }
  float qv[32];
#pragma unroll
  for (int i = 0; i < 32; ++i) qv[i] = s_X[kc][32 + i];

  // L5: 32 -> 1, sigmoid
  float s = b5[0];
#pragma unroll
  for (int i = 0; i < 32; ++i) s = fmaf(w5[i], qv[i], s);
  float y = 1.f / (1.f + __expf(-s));
  float val = act ? y : 0.f;

  // ---- phase 4: mean over the 100 rows ----
#pragma unroll
  for (int off = 32; off > 0; off >>= 1) val += __shfl_down(val, off, 64);
  if (tx == 0) s_part[ty] = val;
  __syncthreads();
  if (tid == 0)
    out[b] = (s_part[0] + s_part[1] + s_part[2] + s_part[3]) * (1.0f / KN);
}

extern "C" void kernel_launch(void* const* d_in, const int* in_sizes, int n_in,
                              void* d_out, int out_size, void* d_ws,
                              size_t ws_size, hipStream_t stream) {
  const float* user_emb = (const float*)d_in[0];
  const float* item_emb = (const float*)d_in[1];
  const float* user_scr = (const float*)d_in[2];
  const float* item_scr = (const float*)d_in[3];
  const float* w1 = (const float*)d_in[4];
  const float* b1 = (const float*)d_in[5];
  const float* w2 = (const float*)d_in[6];
  const float* b2 = (const float*)d_in[7];
  const float* w3 = (const float*)d_in[8];
  const float* b3 = (const float*)d_in[9];
  const float* w4 = (const float*)d_in[10];
  const float* b4 = (const float*)d_in[11];
  const float* w5 = (const float*)d_in[12];
  const float* b5 = (const float*)d_in[13];
  const int* user_idx_t = (const int*)d_in[14];
  const int* item_idx_t = (const int*)d_in[15];
  const int* user_idxs = (const int*)d_in[16];
  const int* item_idxs = (const int*)d_in[17];

  const int B = in_sizes[16];  // 8192
  cnn_fused<<<dim3(B), dim3(256), 0, stream>>>(
      user_emb, item_emb, user_scr, item_scr, w1, b1, w2, b2, w3, b3, w4, b4,
      w5, b5, user_idx_t, item_idx_t, user_idxs, item_idxs, (float*)d_out);
}

// Round 2
// 989.254 us; speedup vs baseline: 6.3807x; 6.3807x over previous
//
#include <hip/hip_runtime.h>
#include <hip/hip_bf16.h>
#include <math.h>

typedef __attribute__((ext_vector_type(8))) short short8;
typedef __attribute__((ext_vector_type(4))) float f32x4;

#define KN 100

__device__ __forceinline__ unsigned short f2bf(float f) {
  __hip_bfloat16 h = __float2bfloat16(f);
  return __builtin_bit_cast(unsigned short, h);
}
__device__ __forceinline__ float bf2f(unsigned short u) {
  unsigned int x = ((unsigned int)u) << 16;
  return __builtin_bit_cast(float, x);
}

// One wave computes output m-tile `w` (rows w*16..w*16+15) of Y = act(A @ B^T + bias).
// A: [128 x (KT*32)] bf16 LDS, row stride sA halfwords (k contiguous).
// Bm: [NT*16 x (KT*32)] bf16 LDS row-major (row = out col n, k contiguous).
// Layouts (gfx950, verified): A-frag m=lane&15,k=quad*8+j; B-frag n=lane&15,k=quad*8+j;
// D: col=lane&15, row=quad*4+reg.
template <int NT, int KT, bool RELU, bool BIAS>
__device__ __forceinline__ void gemm_rowtile(
    const unsigned short* A, int sA, const unsigned short* Bm, int sB,
    unsigned short* Y, int sY, int ycol0, const float* bias, int w, int lane) {
  const int l15 = lane & 15, quad = lane >> 4;
  short8 a[KT];
#pragma unroll
  for (int k = 0; k < KT; ++k)
    a[k] = *reinterpret_cast<const short8*>(A + (w * 16 + l15) * sA + k * 32 + quad * 8);
#pragma unroll
  for (int n = 0; n < NT; ++n) {
    f32x4 acc = {0.f, 0.f, 0.f, 0.f};
#pragma unroll
    for (int k = 0; k < KT; ++k) {
      short8 bfrag = *reinterpret_cast<const short8*>(
          Bm + (n * 16 + l15) * sB + k * 32 + quad * 8);
      acc = __builtin_amdgcn_mfma_f32_16x16x32_bf16(a[k], bfrag, acc, 0, 0, 0);
    }
    const int col = n * 16 + l15;
    float bv = BIAS ? bias[col] : 0.f;
#pragma unroll
    for (int r = 0; r < 4; ++r) {
      int row = w * 16 + quad * 4 + r;
      float v = acc[r] + bv;
      if (RELU) v = fmaxf(v, 0.f);
      Y[row * sY + ycol0 + col] = f2bf(v);
    }
  }
}

__launch_bounds__(512)
__global__ void cnn_mfma(
    const float* __restrict__ user_emb, const float* __restrict__ item_emb,
    const float* __restrict__ user_scr, const float* __restrict__ item_scr,
    const float* __restrict__ w1, const float* __restrict__ b1,
    const float* __restrict__ w2, const float* __restrict__ b2,
    const float* __restrict__ w3, const float* __restrict__ b3,
    const float* __restrict__ w4, const float* __restrict__ b4,
    const float* __restrict__ w5, const float* __restrict__ b5,
    const int* __restrict__ user_idx_t, const int* __restrict__ item_idx_t,
    const int* __restrict__ user_idxs, const int* __restrict__ item_idxs,
    float* __restrict__ out) {
  // ---- LDS (total ~157 KB) ----
  __shared__ __align__(16) unsigned short s_scr[2 * 128 * 136];  // A of pooling; Y1..Y4 alias here later
  __shared__ __align__(16) unsigned short s_Et[64 * 136];        // E^T, one source at a time
  __shared__ __align__(16) unsigned short s_X[128 * 136];        // pooled concat [128 rows x 128 cols]
  __shared__ __align__(16) unsigned short s_W1[64 * 136];
  __shared__ __align__(16) unsigned short s_W2[64 * 72];
  __shared__ __align__(16) unsigned short s_W3[32 * 72];
  __shared__ __align__(16) unsigned short s_W4[32 * 40];
  __shared__ float s_bias[225];  // b1[64] b2[64] b3[32] b4[32] b5[1] w5[32]
  __shared__ int s_nb[2][KN];
  __shared__ float s_red[2];

  const int b = blockIdx.x;
  const int tid = threadIdx.x;
  const int w = tid >> 6;
  const int lane = tid & 63;

  // Y buffers alias the scr region (scr is dead once pooling is done)
  unsigned short* s_Y1 = s_scr;                       // 128 x st72
  unsigned short* s_Y2 = s_scr + 128 * 72;            // 128 x st72
  unsigned short* s_Y3 = s_scr + 2 * 128 * 72;        // 128 x st40
  unsigned short* s_Y4 = s_scr + 2 * 128 * 72 + 128 * 40;  // 128 x st40

  // ---- phase 0: neighbor lists + zero scr/Et + stage weights ----
  const int uidx = user_idxs[b];
  const int iidx = item_idxs[b];
  if (tid < KN) s_nb[0][tid] = user_idx_t[(size_t)uidx * KN + tid];
  else if (tid >= 256 && tid < 256 + KN) s_nb[1][tid - 256] = item_idx_t[(size_t)iidx * KN + (tid - 256)];

  {  // zero scr (pads matter: K-dim zeros) and Et (j>=100 pad)
    int* z0 = (int*)s_scr;
    for (int i = tid; i < 2 * 128 * 136 / 2; i += 512) z0[i] = 0;
    int* z1 = (int*)s_Et;
    for (int i = tid; i < 64 * 136 / 2; i += 512) z1[i] = 0;
  }
  // weights -> LDS bf16 (L2-hot across blocks)
  for (int e = tid; e < 8192; e += 512) s_W1[(e >> 7) * 136 + (e & 127)] = f2bf(w1[e]);
  for (int e = tid; e < 4096; e += 512) s_W2[(e >> 6) * 72 + (e & 63)] = f2bf(w2[e]);
  for (int e = tid; e < 2048; e += 512) s_W3[(e >> 6) * 72 + (e & 63)] = f2bf(w3[e]);
  for (int e = tid; e < 1024; e += 512) s_W4[(e >> 5) * 40 + (e & 31)] = f2bf(w4[e]);
  if (tid < 64) s_bias[tid] = b1[tid];
  else if (tid < 128) s_bias[tid] = b2[tid - 64];
  else if (tid < 160) s_bias[tid] = b3[tid - 128];
  else if (tid < 192) s_bias[tid] = b4[tid - 160];
  else if (tid == 192) s_bias[192] = b5[0];
  else if (tid < 225) s_bias[tid] = w5[tid - 193];
  __syncthreads();

  // ---- phase 1: gather scr (both sources) + user E^T ----
  // scr: 2 x 100 rows x 50 float2, coalesced vector loads -> bf16 LDS
  for (int e = tid; e < 10000; e += 512) {
    const int s = e / 5000;
    const int rem = e - s * 5000;
    const int k = rem / 50;
    const int j2 = rem - k * 50;
    const int row = s_nb[s][k];
    const float2* sp = (const float2*)(s ? item_scr : user_scr);
    float2 v = sp[(size_t)row * 50 + j2];
    unsigned short* dst = s_scr + s * 128 * 136 + k * 136 + j2 * 2;
    dst[0] = f2bf(v.x);
    dst[1] = f2bf(v.y);
  }
  // user embeddings, transposed store Et[d][j]
  for (int r = w; r < KN; r += 8) {
    const int row = s_nb[0][r];
    float v = user_emb[(size_t)row * 64 + lane];
    s_Et[lane * 136 + r] = f2bf(v);
  }
  __syncthreads();

  // ---- phase 2: pool user -> X[:, 0:64] ----
  gemm_rowtile<4, 4, false, false>(s_scr, 136, s_Et, 136, s_X, 136, 0, nullptr, w, lane);
  __syncthreads();

  // ---- phase 3: gather item E^T (overwrite Et) ----
  for (int r = w; r < KN; r += 8) {
    const int row = s_nb[1][r];
    float v = item_emb[(size_t)row * 64 + lane];
    s_Et[lane * 136 + r] = f2bf(v);
  }
  __syncthreads();

  // ---- phase 4: pool item -> X[:, 64:128] ----
  gemm_rowtile<4, 4, false, false>(s_scr + 128 * 136, 136, s_Et, 136, s_X, 136, 64, nullptr, w, lane);
  __syncthreads();

  // ---- phase 5: MLP ----
  gemm_rowtile<4, 4, true, true>(s_X, 136, s_W1, 136, s_Y1, 72, 0, s_bias + 0, w, lane);
  __syncthreads();
  gemm_rowtile<4, 2, true, true>(s_Y1, 72, s_W2, 72, s_Y2, 72, 0, s_bias + 64, w, lane);
  __syncthreads();
  gemm_rowtile<2, 2, true, true>(s_Y2, 72, s_W3, 72, s_Y3, 40, 0, s_bias + 128, w, lane);
  __syncthreads();
  gemm_rowtile<2, 1, true, true>(s_Y3, 40, s_W4, 40, s_Y4, 40, 0, s_bias + 160, w, lane);
  __syncthreads();

  // ---- phase 6: L5 (32 -> 1) + sigmoid + mean ----
  float val = 0.f;
  if (tid < KN) {
    float s = s_bias[192];
#pragma unroll
    for (int i = 0; i < 32; ++i) s = fmaf(bf2f(s_Y4[tid * 40 + i]), s_bias[193 + i], s);
    val = 1.f / (1.f + expf(-s));
  }
  if (w < 2) {
#pragma unroll
    for (int off = 32; off > 0; off >>= 1) val += __shfl_down(val, off, 64);
    if (lane == 0) s_red[w] = val;
  }
  __syncthreads();
  if (tid == 0) out[b] = (s_red[0] + s_red[1]) * (1.0f / KN);
}

extern "C" void kernel_launch(void* const* d_in, const int* in_sizes, int n_in,
                              void* d_out, int out_size, void* d_ws,
                              size_t ws_size, hipStream_t stream) {
  const float* user_emb = (const float*)d_in[0];
  const float* item_emb = (const float*)d_in[1];
  const float* user_scr = (const float*)d_in[2];
  const float* item_scr = (const float*)d_in[3];
  const float* w1 = (const float*)d_in[4];
  const float* b1 = (const float*)d_in[5];
  const float* w2 = (const float*)d_in[6];
  const float* b2 = (const float*)d_in[7];
  const float* w3 = (const float*)d_in[8];
  const float* b3 = (const float*)d_in[9];
  const float* w4 = (const float*)d_in[10];
  const float* b4 = (const float*)d_in[11];
  const float* w5 = (const float*)d_in[12];
  const float* b5 = (const float*)d_in[13];
  const int* user_idx_t = (const int*)d_in[14];
  const int* item_idx_t = (const int*)d_in[15];
  const int* user_idxs = (const int*)d_in[16];
  const int* item_idxs = (const int*)d_in[17];

  const int B = in_sizes[16];  // 8192
  cnn_mfma<<<dim3(B), dim3(512), 0, stream>>>(
      user_emb, item_emb, user_scr, item_scr, w1, b1, w2, b2, w3, b3, w4, b4,
      w5, b5, user_idx_t, item_idx_t, user_idxs, item_idxs, (float*)d_out);
}

// Round 3
// 585.493 us; speedup vs baseline: 10.7808x; 1.6896x over previous
//
#include <hip/hip_runtime.h>
#include <hip/hip_bf16.h>
#include <math.h>

typedef __attribute__((ext_vector_type(8))) short short8;
typedef __attribute__((ext_vector_type(4))) short short4v;
typedef __attribute__((ext_vector_type(4))) float f32x4;

#define KN 100

// ---- LDS layout (halfword offsets). Total 40064 hw = 80128 B ----
#define SCR_OFF 0       // 112 x 136 (A of pooling, one source at a time)
#define ET_OFF  15232   // 64 x 136  (E^T, B of pooling)
#define XU_OFF  23936   // 112 x 72  (pooled user)
#define XI_OFF  32000   // 112 x 72  (pooled item)
#define S_TOT   40064
// Y aliases (dead regions): Y1,Y2 over scr/Et; Y3 over Xu (after post-L1 barrier)
#define Y1_OFF  0       // 112 x 72
#define Y2_OFF  8064    // 112 x 72
#define Y3_OFF  23936   // 112 x 40

// ---- ws layout (bf16 halfwords), weights pre-swizzled to B-frag order ----
#define W1_OFF 0        // 64x128, k_tiles=4
#define W2_OFF 8192     // 64x64,  k_tiles=2
#define W3_OFF 12288    // 32x64,  k_tiles=2
#define W4_OFF 14336    // 32x32,  k_tiles=1

__device__ __forceinline__ unsigned short f2bf(float f) {
  __hip_bfloat16 h = __float2bfloat16(f);
  return __builtin_bit_cast(unsigned short, h);
}

// Convert W1..W4 to bf16 in d_ws, swizzled so MFMA B-frag (ntile,ktile) is a
// contiguous 1KB line: pos = ((n*kt + k)*64 + quad*16 + l15)*8 + j
// (B-frag layout: n = lane&15, k-elem = (lane>>4)*8 + j  [verified m89/m91])
__global__ void prep_weights(const float* __restrict__ w1,
                             const float* __restrict__ w2,
                             const float* __restrict__ w3,
                             const float* __restrict__ w4,
                             unsigned short* __restrict__ ws) {
  int t = blockIdx.x * 256 + threadIdx.x;
  const float* src;
  int rel, o, i, kt, base;
  if (t < 8192)       { src = w1; rel = t;         o = rel >> 7; i = rel & 127; kt = 4; base = W1_OFF; }
  else if (t < 12288) { src = w2; rel = t - 8192;  o = rel >> 6; i = rel & 63;  kt = 2; base = W2_OFF; }
  else if (t < 14336) { src = w3; rel = t - 12288; o = rel >> 6; i = rel & 63;  kt = 2; base = W3_OFF; }
  else if (t < 15360) { src = w4; rel = t - 14336; o = rel >> 5; i = rel & 31;  kt = 1; base = W4_OFF; }
  else return;
  int n = o >> 4, l15 = o & 15, k = i >> 5, quad = (i >> 3) & 3, j = i & 7;
  ws[base + ((n * kt + k) * 64 + quad * 16 + l15) * 8 + j] = f2bf(src[rel]);
}

// One MLP layer for wave w's m-tile: Y[m-tile] = act(A @ W^T + bias).
// A-frags preloaded by caller; W from global (L1-hot, frag-contiguous).
template <int NT, int KT, bool RELU>
__device__ __forceinline__ void mlp_layer(const short8* a,
                                          const unsigned short* __restrict__ gw,
                                          const float* __restrict__ bias,
                                          unsigned short* __restrict__ Y, int sY,
                                          int w, int l15, int quad, int lane) {
#pragma unroll
  for (int n = 0; n < NT; ++n) {
    f32x4 acc = {0.f, 0.f, 0.f, 0.f};
#pragma unroll
    for (int k = 0; k < KT; ++k) {
      short8 bf = *reinterpret_cast<const short8*>(gw + ((n * KT + k) * 64 + lane) * 8);
      acc = __builtin_amdgcn_mfma_f32_16x16x32_bf16(a[k], bf, acc, 0, 0, 0);
    }
    const int col = n * 16 + l15;
    const float bv = bias[col];
#pragma unroll
    for (int r = 0; r < 4; ++r) {
      float v = acc[r] + bv;
      if (RELU) v = fmaxf(v, 0.f);
      Y[(w * 16 + quad * 4 + r) * sY + col] = f2bf(v);
    }
  }
}

__launch_bounds__(448)
__global__ void cnn_mfma2(
    const float* __restrict__ user_emb, const float* __restrict__ item_emb,
    const float* __restrict__ user_scr, const float* __restrict__ item_scr,
    const float* __restrict__ b1, const float* __restrict__ b2,
    const float* __restrict__ b3, const float* __restrict__ b4,
    const float* __restrict__ w5, const float* __restrict__ b5,
    const int* __restrict__ user_idx_t, const int* __restrict__ item_idx_t,
    const int* __restrict__ user_idxs, const int* __restrict__ item_idxs,
    const unsigned short* __restrict__ ws, float* __restrict__ out) {
  __shared__ __align__(16) unsigned short S[S_TOT];
  __shared__ int s_nb[2][KN];
  __shared__ float s_red[7];

  const int b = blockIdx.x;
  const int tid = threadIdx.x;
  const int w = tid >> 6;
  const int lane = tid & 63;
  const int l15 = lane & 15, quad = lane >> 4;

  // ---- phase 0: neighbor lists + one-time zero of scr+Et (pads persist) ----
  if (tid < KN) s_nb[0][tid] = user_idx_t[(size_t)user_idxs[b] * KN + tid];
  else if (tid >= 224 && tid < 224 + KN)
    s_nb[1][tid - 224] = item_idx_t[(size_t)item_idxs[b] * KN + (tid - 224)];
  {
    int* z = (int*)S;
    for (int i = tid; i < (ET_OFF + 64 * 136) / 2; i += 448) z[i] = 0;
  }
  __syncthreads();

  // ================= source 0 (user) then source 1 (item) =================
#pragma unroll 1
  for (int src = 0; src < 2; ++src) {
    const float* scr = src ? item_scr : user_scr;
    const float* emb = src ? item_emb : user_emb;
    const int* nb = s_nb[src];
    const int xoff = src ? XI_OFF : XU_OFF;

    // gather scr rows (fp32 float4 -> bf16 LDS, k-contiguous)
    for (int e = tid; e < 2500; e += 448) {
      const int k = e / 25, j4 = e - k * 25;
      float4 v = reinterpret_cast<const float4*>(scr)[(size_t)nb[k] * 25 + j4];
      short4v h;
      h[0] = (short)f2bf(v.x); h[1] = (short)f2bf(v.y);
      h[2] = (short)f2bf(v.z); h[3] = (short)f2bf(v.w);
      *reinterpret_cast<short4v*>(S + SCR_OFF + k * 136 + j4 * 4) = h;
    }
    // gather E^T (coalesced 256B row loads, transposed b16 store)
    for (int r = w; r < KN; r += 7) {
      float v = emb[(size_t)nb[r] * 64 + lane];
      S[ET_OFF + lane * 136 + r] = f2bf(v);
    }
    __syncthreads();

    // pool: X[k][d] = sum_j scr[k][j] * Et[d][j]   (M=112, N=64, K=128)
    {
      short8 a[4];
#pragma unroll
      for (int k = 0; k < 4; ++k)
        a[k] = *reinterpret_cast<const short8*>(S + SCR_OFF + (w * 16 + l15) * 136 + k * 32 + quad * 8);
#pragma unroll
      for (int n = 0; n < 4; ++n) {
        f32x4 acc = {0.f, 0.f, 0.f, 0.f};
#pragma unroll
        for (int k = 0; k < 4; ++k) {
          short8 bf = *reinterpret_cast<const short8*>(S + ET_OFF + (n * 16 + l15) * 136 + k * 32 + quad * 8);
          acc = __builtin_amdgcn_mfma_f32_16x16x32_bf16(a[k], bf, acc, 0, 0, 0);
        }
#pragma unroll
        for (int r = 0; r < 4; ++r)
          S[xoff + (w * 16 + quad * 4 + r) * 72 + n * 16 + l15] = f2bf(acc[r]);
      }
    }
    __syncthreads();  // src 0: scr/Et about to be overwritten; src 1: Y1 aliases scr
  }

  // ---- MLP: wave-private rows, weights from global (L1-hot) ----
  // L1: 128 -> 64
  {
    short8 a[4];
    a[0] = *reinterpret_cast<const short8*>(S + XU_OFF + (w * 16 + l15) * 72 + quad * 8);
    a[1] = *reinterpret_cast<const short8*>(S + XU_OFF + (w * 16 + l15) * 72 + 32 + quad * 8);
    a[2] = *reinterpret_cast<const short8*>(S + XI_OFF + (w * 16 + l15) * 72 + quad * 8);
    a[3] = *reinterpret_cast<const short8*>(S + XI_OFF + (w * 16 + l15) * 72 + 32 + quad * 8);
    mlp_layer<4, 4, true>(a, ws + W1_OFF, b1, S + Y1_OFF, 72, w, l15, quad, lane);
  }
  __syncthreads();  // frees X region for Y3 aliasing

  // L2: 64 -> 64
  {
    short8 a[2];
    a[0] = *reinterpret_cast<const short8*>(S + Y1_OFF + (w * 16 + l15) * 72 + quad * 8);
    a[1] = *reinterpret_cast<const short8*>(S + Y1_OFF + (w * 16 + l15) * 72 + 32 + quad * 8);
    mlp_layer<4, 2, true>(a, ws + W2_OFF, b2, S + Y2_OFF, 72, w, l15, quad, lane);
  }
  // L3: 64 -> 32
  {
    short8 a[2];
    a[0] = *reinterpret_cast<const short8*>(S + Y2_OFF + (w * 16 + l15) * 72 + quad * 8);
    a[1] = *reinterpret_cast<const short8*>(S + Y2_OFF + (w * 16 + l15) * 72 + 32 + quad * 8);
    mlp_layer<2, 2, true>(a, ws + W3_OFF, b3, S + Y3_OFF, 40, w, l15, quad, lane);
  }
  // L4 (32->32, relu) fused with L5 (32->1) + sigmoid, all in registers
  {
    short8 a = *reinterpret_cast<const short8*>(S + Y3_OFF + (w * 16 + l15) * 40 + quad * 8);
    float dot[4] = {0.f, 0.f, 0.f, 0.f};
#pragma unroll
    for (int n = 0; n < 2; ++n) {
      f32x4 acc = {0.f, 0.f, 0.f, 0.f};
      short8 bf = *reinterpret_cast<const short8*>(ws + W4_OFF + (n * 64 + lane) * 8);
      acc = __builtin_amdgcn_mfma_f32_16x16x32_bf16(a, bf, acc, 0, 0, 0);
      const int col = n * 16 + l15;
      const float bv = b4[col], wv = w5[col];
#pragma unroll
      for (int r = 0; r < 4; ++r) {
        float v = fmaxf(acc[r] + bv, 0.f);
        dot[r] = fmaf(v, wv, dot[r]);
      }
    }
    float wsum = 0.f;
    const float bb5 = b5[0];
#pragma unroll
    for (int r = 0; r < 4; ++r) {
      float s = dot[r];
      s += __shfl_xor(s, 1, 64);
      s += __shfl_xor(s, 2, 64);
      s += __shfl_xor(s, 4, 64);
      s += __shfl_xor(s, 8, 64);
      const int row = w * 16 + quad * 4 + r;
      if (l15 == 0 && row < KN) wsum += 1.f / (1.f + expf(-(s + bb5)));
    }
    wsum += __shfl_xor(wsum, 16, 64);
    wsum += __shfl_xor(wsum, 32, 64);
    if (lane == 0) s_red[w] = wsum;
  }
  __syncthreads();
  if (tid == 0) {
    float t = 0.f;
#pragma unroll
    for (int i = 0; i < 7; ++i) t += s_red[i];
    out[b] = t * (1.0f / KN);
  }
}

extern "C" void kernel_launch(void* const* d_in, const int* in_sizes, int n_in,
                              void* d_out, int out_size, void* d_ws,
                              size_t ws_size, hipStream_t stream) {
  const float* user_emb = (const float*)d_in[0];
  const float* item_emb = (const float*)d_in[1];
  const float* user_scr = (const float*)d_in[2];
  const float* item_scr = (const float*)d_in[3];
  const float* w1 = (const float*)d_in[4];
  const float* b1 = (const float*)d_in[5];
  const float* w2 = (const float*)d_in[6];
  const float* b2 = (const float*)d_in[7];
  const float* w3 = (const float*)d_in[8];
  const float* b3 = (const float*)d_in[9];
  const float* w4 = (const float*)d_in[10];
  const float* b4 = (const float*)d_in[11];
  const float* w5 = (const float*)d_in[12];
  const float* b5 = (const float*)d_in[13];
  const int* user_idx_t = (const int*)d_in[14];
  const int* item_idx_t = (const int*)d_in[15];
  const int* user_idxs = (const int*)d_in[16];
  const int* item_idxs = (const int*)d_in[17];
  unsigned short* wsw = (unsigned short*)d_ws;

  prep_weights<<<dim3(60), dim3(256), 0, stream>>>(w1, w2, w3, w4, wsw);

  const int B = in_sizes[16];  // 8192
  cnn_mfma2<<<dim3(B), dim3(448), 0, stream>>>(
      user_emb, item_emb, user_scr, item_scr, b1, b2, b3, b4, w5, b5,
      user_idx_t, item_idx_t, user_idxs, item_idxs, wsw, (float*)d_out);
}

// Round 4
// 379.173 us; speedup vs baseline: 16.6470x; 1.5441x over previous
//
#include <hip/hip_runtime.h>
#include <hip/hip_bf16.h>
#include <math.h>

typedef __attribute__((ext_vector_type(8))) short short8;
typedef __attribute__((ext_vector_type(4))) float f32x4;

#define KN 100

// ---- ws layout (halfword units) ----
#define W1_OFF 0         // 64x128 bf16, B-frag swizzled, kt=4
#define W2_OFF 8192      // 64x64, kt=2
#define W3_OFF 12288     // 32x64, kt=2
#define W4_OFF 14336     // 32x32, kt=1
#define SCRU_OFF 16384                        // 100000 x 128 bf16 (zero-padded j>=100)
#define SCRI_OFF (SCRU_OFF + 100000 * 128)    // 50000 x 128
#define EMBU_OFF (SCRI_OFF + 50000 * 128)     // 100000 x 64 bf16
#define EMBI_OFF (EMBU_OFF + 100000 * 64)     // 50000 x 64
// total end: 28,816,384 hw = 57.6 MB

// ---- LDS layout (halfword offsets) ----
#define ET_OFF 0                  // 64 x 136 (E^T for current source)
#define XU_OFF (64 * 136)         // 112 x 72 ; later Y1/Y3 alias (wave-private bands)
#define XI_OFF (XU_OFF + 112 * 72)// 112 x 72 ; later Y2 alias
#define S_TOT  (XI_OFF + 112 * 72)// 24832 hw = 49664 B

__device__ __forceinline__ unsigned short f2bf(float f) {
  __hip_bfloat16 h = __float2bfloat16(f);
  return __builtin_bit_cast(unsigned short, h);
}

__device__ __forceinline__ void st8(unsigned short* d, float4 a, float4 b) {
  short8 h;
  h[0] = (short)f2bf(a.x); h[1] = (short)f2bf(a.y);
  h[2] = (short)f2bf(a.z); h[3] = (short)f2bf(a.w);
  h[4] = (short)f2bf(b.x); h[5] = (short)f2bf(b.y);
  h[6] = (short)f2bf(b.z); h[7] = (short)f2bf(b.w);
  *reinterpret_cast<short8*>(d) = h;
}

// Streaming prep: weights (B-frag swizzle) + scr (bf16, pad to 128) + emb (bf16).
__global__ void prep(const float* __restrict__ w1, const float* __restrict__ w2,
                     const float* __restrict__ w3, const float* __restrict__ w4,
                     const float* __restrict__ uscr, const float* __restrict__ iscr,
                     const float* __restrict__ uemb, const float* __restrict__ iemb,
                     unsigned short* __restrict__ ws) {
  int t = blockIdx.x * 256 + threadIdx.x;
  if (t < 15360) {
    // weights: B-frag (n = lane&15, k-elem = (lane>>4)*8 + j) contiguous per frag
    const float* src; int rel, o, i, kt, base;
    if (t < 8192)       { src = w1; rel = t;         o = rel >> 7; i = rel & 127; kt = 4; base = W1_OFF; }
    else if (t < 12288) { src = w2; rel = t - 8192;  o = rel >> 6; i = rel & 63;  kt = 2; base = W2_OFF; }
    else if (t < 14336) { src = w3; rel = t - 12288; o = rel >> 6; i = rel & 63;  kt = 2; base = W3_OFF; }
    else                { src = w4; rel = t - 14336; o = rel >> 5; i = rel & 31;  kt = 1; base = W4_OFF; }
    int n = o >> 4, l15 = o & 15, k = i >> 5, quad = (i >> 3) & 3, j = i & 7;
    ws[base + ((n * kt + k) * 64 + quad * 16 + l15) * 8 + j] = f2bf(src[rel]);
    return;
  }
  int rel = t - 15360;
  const float4 z4 = {0.f, 0.f, 0.f, 0.f};
  if (rel < 2400000) {  // scr: 16 threads/row, 8 outputs each (128 cols, pad >=100)
    const float* src; unsigned short* dst; int row, g;
    if (rel < 1600000) {
      row = rel >> 4; g = rel & 15;
      src = uscr + (size_t)row * 100;
      dst = ws + SCRU_OFF + (size_t)row * 128 + g * 8;
    } else {
      int q = rel - 1600000; row = q >> 4; g = q & 15;
      src = iscr + (size_t)row * 100;
      dst = ws + SCRI_OFF + (size_t)row * 128 + g * 8;
    }
    float4 va = (g < 13) ? *reinterpret_cast<const float4*>(src + g * 8) : z4;
    float4 vb = (g < 12) ? *reinterpret_cast<const float4*>(src + g * 8 + 4) : z4;
    st8(dst, va, vb);
    return;
  }
  rel -= 2400000;
  if (rel < 1200000) {  // emb: 8 threads/row, 8 outputs each (64 cols)
    const float* src; unsigned short* dst; int row, g;
    if (rel < 800000) {
      row = rel >> 3; g = rel & 7;
      src = uemb + (size_t)row * 64;
      dst = ws + EMBU_OFF + (size_t)row * 64 + g * 8;
    } else {
      int q = rel - 800000; row = q >> 3; g = q & 7;
      src = iemb + (size_t)row * 64;
      dst = ws + EMBI_OFF + (size_t)row * 64 + g * 8;
    }
    float4 va = *reinterpret_cast<const float4*>(src + g * 8);
    float4 vb = *reinterpret_cast<const float4*>(src + g * 8 + 4);
    st8(dst, va, vb);
  }
}

// One MLP layer for wave w's 16-row band: Y = act(A @ W^T + bias).
template <int NT, int KT, bool RELU>
__device__ __forceinline__ void mlp_layer(const short8* a,
                                          const unsigned short* __restrict__ gw,
                                          const float* __restrict__ bias,
                                          unsigned short* __restrict__ Y, int sY,
                                          int w, int l15, int quad, int lane) {
#pragma unroll
  for (int n = 0; n < NT; ++n) {
    f32x4 acc = {0.f, 0.f, 0.f, 0.f};
#pragma unroll
    for (int k = 0; k < KT; ++k) {
      short8 bf = *reinterpret_cast<const short8*>(gw + ((n * KT + k) * 64 + lane) * 8);
      acc = __builtin_amdgcn_mfma_f32_16x16x32_bf16(a[k], bf, acc, 0, 0, 0);
    }
    const int col = n * 16 + l15;
    const float bv = bias[col];
#pragma unroll
    for (int r = 0; r < 4; ++r) {
      float v = acc[r] + bv;
      if (RELU) v = fmaxf(v, 0.f);
      Y[(w * 16 + quad * 4 + r) * sY + col] = f2bf(v);
    }
  }
}

__launch_bounds__(448)
__global__ void cnn_mfma3(
    const unsigned short* __restrict__ ws,
    const float* __restrict__ b1, const float* __restrict__ b2,
    const float* __restrict__ b3, const float* __restrict__ b4,
    const float* __restrict__ w5, const float* __restrict__ b5,
    const int* __restrict__ user_idx_t, const int* __restrict__ item_idx_t,
    const int* __restrict__ user_idxs, const int* __restrict__ item_idxs,
    float* __restrict__ out) {
  __shared__ __align__(16) unsigned short S[S_TOT];
  __shared__ int s_nb[2][112];
  __shared__ float s_red[7];

  const int b = blockIdx.x;
  const int tid = threadIdx.x;
  const int w = tid >> 6;
  const int lane = tid & 63;
  const int l15 = lane & 15, quad = lane >> 4;

  // ---- P0: neighbor lists (pad -> 0) + zero Et once (pads must be finite) ----
  if (tid < 112) {
    s_nb[0][tid] = (tid < KN) ? user_idx_t[(size_t)user_idxs[b] * KN + tid] : 0;
  } else if (tid >= 128 && tid < 240) {
    int i = tid - 128;
    s_nb[1][i] = (i < KN) ? item_idx_t[(size_t)item_idxs[b] * KN + i] : 0;
  }
  {
    int* z = (int*)S;
    for (int i = tid; i < (64 * 136) / 2; i += 448) z[i] = 0;
  }
  __syncthreads();

  const int mrow = w * 16 + l15;  // this lane's pooling output row (neighbor idx)
  const int c = lane & 31, half = lane >> 5;

#pragma unroll 1
  for (int src = 0; src < 2; ++src) {
    const unsigned short* scrb = ws + (src ? SCRI_OFF : SCRU_OFF);
    const unsigned short* embb = ws + (src ? EMBI_OFF : EMBU_OFF);
    const int* nb = s_nb[src];

    // A-frags straight from global bf16 scr (16B contiguous per lane, prefetched
    // here so the Et-staging latency below hides them)
    short8 a[4];
    {
      const unsigned short* arow = scrb + (size_t)nb[mrow] * 128;
#pragma unroll
      for (int k = 0; k < 4; ++k)
        a[k] = *reinterpret_cast<const short8*>(arow + k * 32 + quad * 8);
    }

    // Et staging: 2 rows per round (32 lanes x 4B per row), transposed bf16 store
#pragma unroll
    for (int rr = 0; rr < 8; ++rr) {
      const int rbase = w + rr * 7;
      if (rbase < 50) {
        const int r = rbase * 2 + half;
        unsigned int v = *reinterpret_cast<const unsigned int*>(
            embb + (size_t)nb[r] * 64 + c * 2);
        S[ET_OFF + (2 * c) * 136 + r] = (unsigned short)(v & 0xffffu);
        S[ET_OFF + (2 * c + 1) * 136 + r] = (unsigned short)(v >> 16);
      }
    }
    __syncthreads();

    // pool: X[m][d] = sum_j scr[nb[m]][j] * emb[nb[j]][d]  (M=112, N=64, K=128)
    const int xoff = src ? XI_OFF : XU_OFF;
#pragma unroll
    for (int n = 0; n < 4; ++n) {
      f32x4 acc = {0.f, 0.f, 0.f, 0.f};
#pragma unroll
      for (int k = 0; k < 4; ++k) {
        short8 bf = *reinterpret_cast<const short8*>(
            S + ET_OFF + (n * 16 + l15) * 136 + k * 32 + quad * 8);
        acc = __builtin_amdgcn_mfma_f32_16x16x32_bf16(a[k], bf, acc, 0, 0, 0);
      }
#pragma unroll
      for (int r = 0; r < 4; ++r)
        S[xoff + (w * 16 + quad * 4 + r) * 72 + n * 16 + l15] = f2bf(acc[r]);
    }
    if (src == 0) __syncthreads();  // all waves done reading Et(u) before overwrite
  }

  // ---- MLP: wave-private 16-row bands, zero barriers. Aliasing per band:
  // L1 reads XU+XI -> writes Y1 over XU band; L2 reads Y1 -> Y2 over XI band;
  // L3 reads Y2 -> Y3 over XU band; L4+L5 in registers.
  {
    short8 a[4];
    a[0] = *reinterpret_cast<const short8*>(S + XU_OFF + (w * 16 + l15) * 72 + quad * 8);
    a[1] = *reinterpret_cast<const short8*>(S + XU_OFF + (w * 16 + l15) * 72 + 32 + quad * 8);
    a[2] = *reinterpret_cast<const short8*>(S + XI_OFF + (w * 16 + l15) * 72 + quad * 8);
    a[3] = *reinterpret_cast<const short8*>(S + XI_OFF + (w * 16 + l15) * 72 + 32 + quad * 8);
    mlp_layer<4, 4, true>(a, ws + W1_OFF, b1, S + XU_OFF, 72, w, l15, quad, lane);
  }
  {
    short8 a[2];
    a[0] = *reinterpret_cast<const short8*>(S + XU_OFF + (w * 16 + l15) * 72 + quad * 8);
    a[1] = *reinterpret_cast<const short8*>(S + XU_OFF + (w * 16 + l15) * 72 + 32 + quad * 8);
    mlp_layer<4, 2, true>(a, ws + W2_OFF, b2, S + XI_OFF, 72, w, l15, quad, lane);
  }
  {
    short8 a[2];
    a[0] = *reinterpret_cast<const short8*>(S + XI_OFF + (w * 16 + l15) * 72 + quad * 8);
    a[1] = *reinterpret_cast<const short8*>(S + XI_OFF + (w * 16 + l15) * 72 + 32 + quad * 8);
    mlp_layer<2, 2, true>(a, ws + W3_OFF, b3, S + XU_OFF, 72, w, l15, quad, lane);
  }
  // L4 (32->32, relu) fused with L5 (32->1) + sigmoid + partial mean
  {
    short8 a = *reinterpret_cast<const short8*>(S + XU_OFF + (w * 16 + l15) * 72 + quad * 8);
    float dot[4] = {0.f, 0.f, 0.f, 0.f};
#pragma unroll
    for (int n = 0; n < 2; ++n) {
      f32x4 acc = {0.f, 0.f, 0.f, 0.f};
      short8 bf = *reinterpret_cast<const short8*>(ws + W4_OFF + (n * 64 + lane) * 8);
      acc = __builtin_amdgcn_mfma_f32_16x16x32_bf16(a, bf, acc, 0, 0, 0);
      const int col = n * 16 + l15;
      const float bv = b4[col], wv = w5[col];
#pragma unroll
      for (int r = 0; r < 4; ++r) {
        float v = fmaxf(acc[r] + bv, 0.f);
        dot[r] = fmaf(v, wv, dot[r]);
      }
    }
    float wsum = 0.f;
    const float bb5 = b5[0];
#pragma unroll
    for (int r = 0; r < 4; ++r) {
      float s = dot[r];
      s += __shfl_xor(s, 1, 64);
      s += __shfl_xor(s, 2, 64);
      s += __shfl_xor(s, 4, 64);
      s += __shfl_xor(s, 8, 64);
      const int row = w * 16 + quad * 4 + r;
      if (l15 == 0 && row < KN) wsum += 1.f / (1.f + expf(-(s + bb5)));
    }
    wsum += __shfl_xor(wsum, 16, 64);
    wsum += __shfl_xor(wsum, 32, 64);
    if (lane == 0) s_red[w] = wsum;
  }
  __syncthreads();
  if (tid == 0) {
    float t = 0.f;
#pragma unroll
    for (int i = 0; i < 7; ++i) t += s_red[i];
    out[b] = t * (1.0f / KN);
  }
}

extern "C" void kernel_launch(void* const* d_in, const int* in_sizes, int n_in,
                              void* d_out, int out_size, void* d_ws,
                              size_t ws_size, hipStream_t stream) {
  const float* user_emb = (const float*)d_in[0];
  const float* item_emb = (const float*)d_in[1];
  const float* user_scr = (const float*)d_in[2];
  const float* item_scr = (const float*)d_in[3];
  const float* w1 = (const float*)d_in[4];
  const float* b1 = (const float*)d_in[5];
  const float* w2 = (const float*)d_in[6];
  const float* b2 = (const float*)d_in[7];
  const float* w3 = (const float*)d_in[8];
  const float* b3 = (const float*)d_in[9];
  const float* w4 = (const float*)d_in[10];
  const float* b4 = (const float*)d_in[11];
  const float* w5 = (const float*)d_in[12];
  const float* b5 = (const float*)d_in[13];
  const int* user_idx_t = (const int*)d_in[14];
  const int* item_idx_t = (const int*)d_in[15];
  const int* user_idxs = (const int*)d_in[16];
  const int* item_idxs = (const int*)d_in[17];
  unsigned short* wsw = (unsigned short*)d_ws;

  // prep: 15360 (weights) + 2.4M (scr) + 1.2M (emb) threads
  prep<<<dim3((15360 + 2400000 + 1200000 + 255) / 256), dim3(256), 0, stream>>>(
      w1, w2, w3, w4, user_scr, item_scr, user_emb, item_emb, wsw);

  const int B = in_sizes[16];  // 8192
  cnn_mfma3<<<dim3(B), dim3(448), 0, stream>>>(
      wsw, b1, b2, b3, b4, w5, b5, user_idx_t, item_idx_t, user_idxs,
      item_idxs, (float*)d_out);
}